// Round 4
// baseline (76.665 us; speedup 1.0000x reference)
//
#include <hip/hip_runtime.h>
#include <math.h>

// Problem constants
#define E      4096
#define BATCH  8
#define COLB   256            // columns per block (64 lanes x float4)

typedef float f32x4 __attribute__((ext_vector_type(4)));

// ---------------------------------------------------------------------------
// Kernel A: split-K partial GEMM for  yin @ (w + alpha*hebb)
//   partial[kBlock][b][col] = sum_{k in kBlock} yin[b][k] * (w[k][col] + alpha[k][col]*hebb[k][col])
// Deterministic: fixed partitioning, fixed reduction order, no atomics.
// w/alpha are streamed with NON-TEMPORAL loads (read exactly once, keep them
// out of L3 so hebb + hebb_out stay resident across kernels and replays).
// hebb uses normal loads (re-read by kernel C and next replay's A -> want L3).
// ---------------------------------------------------------------------------
template <int KB>
__global__ __launch_bounds__(256, 4) void partial_gemm_kernel(
    const float* __restrict__ yin,
    const float* __restrict__ hebb,
    const float* __restrict__ w,
    const float* __restrict__ alpha,
    float* __restrict__ partial)          // [E/KB][BATCH][E]
{
    __shared__ __align__(16) float s_yin[BATCH * KB];
    __shared__ __align__(16) float s_red[4 * BATCH * COLB];  // 32 KiB

    const int t    = threadIdx.x;
    const int lane = t & 63;
    const int wave = t >> 6;              // 0..3
    const int colBlock = blockIdx.x;      // 0..15
    const int kBlock   = blockIdx.y;      // 0..E/KB-1

    // Stage yin[b][kBlock*KB .. +KB) into LDS (float4 per thread).
    {
        const int nf4 = BATCH * KB / 4;
        for (int i = t; i < nf4; i += 256) {
            const int b   = (i * 4) / KB;
            const int off = (i * 4) % KB;
            const float4 v = *reinterpret_cast<const float4*>(
                yin + (size_t)b * E + (size_t)kBlock * KB + off);
            *reinterpret_cast<float4*>(&s_yin[b * KB + off]) = v;
        }
    }
    __syncthreads();

    const int col0 = colBlock * COLB + lane * 4;

    float4 acc[BATCH];
#pragma unroll
    for (int b = 0; b < BATCH; ++b) acc[b] = make_float4(0.f, 0.f, 0.f, 0.f);

    const int kLocal0 = wave * (KB / 4);  // KB/4 k's per wave

    // Groups of 4 k's: issue all 12 float4 loads, then consume.
#pragma unroll
    for (int g = 0; g < KB / 16; ++g) {
        f32x4 w4[4], a4[4];
        float4 h4[4];
#pragma unroll
        for (int u = 0; u < 4; ++u) {
            const size_t row = (size_t)(kBlock * KB + kLocal0 + g * 4 + u) * E + col0;
            w4[u] = __builtin_nontemporal_load(reinterpret_cast<const f32x4*>(w + row));
            a4[u] = __builtin_nontemporal_load(reinterpret_cast<const f32x4*>(alpha + row));
            h4[u] = *reinterpret_cast<const float4*>(hebb + row);
        }
#pragma unroll
        for (int u = 0; u < 4; ++u) {
            float4 m;
            m.x = w4[u].x + a4[u].x * h4[u].x;
            m.y = w4[u].y + a4[u].y * h4[u].y;
            m.z = w4[u].z + a4[u].z * h4[u].z;
            m.w = w4[u].w + a4[u].w * h4[u].w;
            const int kL = kLocal0 + g * 4 + u;
#pragma unroll
            for (int b = 0; b < BATCH; ++b) {
                const float yv = s_yin[b * KB + kL];
                acc[b].x = fmaf(yv, m.x, acc[b].x);
                acc[b].y = fmaf(yv, m.y, acc[b].y);
                acc[b].z = fmaf(yv, m.z, acc[b].z);
                acc[b].w = fmaf(yv, m.w, acc[b].w);
            }
        }
    }

    // Store per-wave accumulators: layout s_red[wave][b][COLB]
#pragma unroll
    for (int b = 0; b < BATCH; ++b) {
        *reinterpret_cast<float4*>(&s_red[(wave * BATCH + b) * COLB + lane * 4]) = acc[b];
    }
    __syncthreads();

    // Reduce 4 waves -> partial.  col = t (coalesced LDS + global).
#pragma unroll
    for (int b = 0; b < BATCH; ++b) {
        const int col = t;
        const float s = s_red[(0 * BATCH + b) * COLB + col]
                      + s_red[(1 * BATCH + b) * COLB + col]
                      + s_red[(2 * BATCH + b) * COLB + col]
                      + s_red[(3 * BATCH + b) * COLB + col];
        partial[((size_t)kBlock * BATCH + b) * E + colBlock * COLB + col] = s;
    }
}

// ---------------------------------------------------------------------------
// Kernel B: yout[b][j] = tanh(input[b][j] + sum_kb partial[kb][b][j])
// ---------------------------------------------------------------------------
template <int NKB>
__global__ __launch_bounds__(256) void finalize_yout_kernel(
    const float* __restrict__ input,
    const float* __restrict__ partial,
    float* __restrict__ yout)
{
    const int idx = blockIdx.x * 256 + threadIdx.x;   // 0..32767
    const int b = idx >> 12;
    const int j = idx & (E - 1);

    float s = input[idx];
#pragma unroll 8
    for (int kb = 0; kb < NKB; ++kb)
        s += partial[((size_t)kb * BATCH + b) * E + j];

    yout[idx] = tanhf(s);
}

// ---------------------------------------------------------------------------
// Kernel C: hebb_new = (1-eta)*hebb + eta * outer(yin[0], yout[0])
// hebb read: normal (L3-resident from kernel A). hebb_out store: non-temporal
// (never re-read on device; keep it from evicting hebb).
// ---------------------------------------------------------------------------
__global__ __launch_bounds__(256) void hebb_update_kernel(
    const float* __restrict__ hebb,
    const float* __restrict__ yin,
    const float* __restrict__ yout,       // d_out row 0 (already written)
    const float* __restrict__ eta_p,
    float* __restrict__ hebb_out)
{
    const float eta  = eta_p[0];
    const float keep = 1.0f - eta;

    const size_t N4 = (size_t)E * E / 4;  // 4,194,304 float4's
    const size_t stride = (size_t)gridDim.x * blockDim.x;

    for (size_t i4 = (size_t)blockIdx.x * blockDim.x + threadIdx.x; i4 < N4; i4 += stride) {
        const size_t base = i4 * 4;
        const int row = (int)(base >> 12);          // i index
        const int jcol = (int)(base & (E - 1));     // j index (multiple of 4)

        const float y0 = yin[row] * eta;            // eta * yin[0][row]
        const float4 h  = *reinterpret_cast<const float4*>(hebb + base);
        const float4 yo = *reinterpret_cast<const float4*>(yout + jcol);

        f32x4 r;
        r.x = fmaf(y0, yo.x, keep * h.x);
        r.y = fmaf(y0, yo.y, keep * h.y);
        r.z = fmaf(y0, yo.z, keep * h.z);
        r.w = fmaf(y0, yo.w, keep * h.w);

        __builtin_nontemporal_store(r, reinterpret_cast<f32x4*>(hebb_out + base));
    }
}

// ---------------------------------------------------------------------------
extern "C" void kernel_launch(void* const* d_in, const int* in_sizes, int n_in,
                              void* d_out, int out_size, void* d_ws, size_t ws_size,
                              hipStream_t stream) {
    const float* input = (const float*)d_in[0];   // [8, 4096]
    const float* yin   = (const float*)d_in[1];   // [8, 4096]
    const float* hebb  = (const float*)d_in[2];   // [4096, 4096]
    const float* w     = (const float*)d_in[3];   // [4096, 4096]
    const float* alpha = (const float*)d_in[4];   // [4096, 4096]
    const float* eta   = (const float*)d_in[5];   // [1]

    float* out      = (float*)d_out;
    float* yout     = out;                               // 8*4096 floats
    float* hebb_out = out + (size_t)BATCH * E;           // 4096*4096 floats
    float* partial  = (float*)d_ws;                      // 4 MiB (KB=128)

    // KB=128: 512 blocks (R1's faster config), partial = 4 MiB.
    dim3 gridA(E / COLB, E / 128);   // 16 x 32
    partial_gemm_kernel<128><<<gridA, 256, 0, stream>>>(yin, hebb, w, alpha, partial);

    finalize_yout_kernel<32><<<(BATCH * E) / 256, 256, 0, stream>>>(input, partial, yout);

    hebb_update_kernel<<<2048, 256, 0, stream>>>(hebb, yin, yout, eta, hebb_out);
}

// Round 5
// 76.467 us; speedup vs baseline: 1.0026x; 1.0026x over previous
//
#include <hip/hip_runtime.h>
#include <math.h>

// Problem constants
#define E      4096
#define BATCH  8
#define COLB   256            // columns per block (64 lanes x float4)

typedef float f32x4 __attribute__((ext_vector_type(4)));

// ---------------------------------------------------------------------------
// Kernel A: split-K partial GEMM for  yin @ (w + alpha*hebb)
//   partial[kBlock][b][col] = sum_{k in kBlock} yin[b][k] * (w[k][col] + alpha[k][col]*hebb[k][col])
// Deterministic: fixed partitioning, fixed reduction order, no atomics.
// w/alpha: NON-TEMPORAL loads (read-once streams; keep them out of L3 so
// hebb + hebb_out dirty lines stay resident across kernels and replays).
// hebb: NORMAL loads (re-read by kernel C and by next replay's A -> want L3).
// hebb_out (kernel C): NORMAL stores (dirty lines park in L3, write-back
// elided when overwritten next replay — the nt-store in R4 broke this).
// ---------------------------------------------------------------------------
template <int KB>
__global__ __launch_bounds__(256, 4) void partial_gemm_kernel(
    const float* __restrict__ yin,
    const float* __restrict__ hebb,
    const float* __restrict__ w,
    const float* __restrict__ alpha,
    float* __restrict__ partial)          // [E/KB][BATCH][E]
{
    __shared__ __align__(16) float s_yin[BATCH * KB];
    __shared__ __align__(16) float s_red[4 * BATCH * COLB];  // 32 KiB

    const int t    = threadIdx.x;
    const int lane = t & 63;
    const int wave = t >> 6;              // 0..3
    const int colBlock = blockIdx.x;      // 0..15
    const int kBlock   = blockIdx.y;      // 0..E/KB-1

    // Stage yin[b][kBlock*KB .. +KB) into LDS (float4 per thread).
    {
        const int nf4 = BATCH * KB / 4;
        for (int i = t; i < nf4; i += 256) {
            const int b   = (i * 4) / KB;
            const int off = (i * 4) % KB;
            const float4 v = *reinterpret_cast<const float4*>(
                yin + (size_t)b * E + (size_t)kBlock * KB + off);
            *reinterpret_cast<float4*>(&s_yin[b * KB + off]) = v;
        }
    }
    __syncthreads();

    const int col0 = colBlock * COLB + lane * 4;

    float4 acc[BATCH];
#pragma unroll
    for (int b = 0; b < BATCH; ++b) acc[b] = make_float4(0.f, 0.f, 0.f, 0.f);

    const int kLocal0 = wave * (KB / 4);  // KB/4 k's per wave

    // Groups of 4 k's: issue all 12 float4 loads, then consume.
#pragma unroll
    for (int g = 0; g < KB / 16; ++g) {
        f32x4 w4[4], a4[4];
        float4 h4[4];
#pragma unroll
        for (int u = 0; u < 4; ++u) {
            const size_t row = (size_t)(kBlock * KB + kLocal0 + g * 4 + u) * E + col0;
            w4[u] = __builtin_nontemporal_load(reinterpret_cast<const f32x4*>(w + row));
            a4[u] = __builtin_nontemporal_load(reinterpret_cast<const f32x4*>(alpha + row));
            h4[u] = *reinterpret_cast<const float4*>(hebb + row);
        }
#pragma unroll
        for (int u = 0; u < 4; ++u) {
            float4 m;
            m.x = w4[u].x + a4[u].x * h4[u].x;
            m.y = w4[u].y + a4[u].y * h4[u].y;
            m.z = w4[u].z + a4[u].z * h4[u].z;
            m.w = w4[u].w + a4[u].w * h4[u].w;
            const int kL = kLocal0 + g * 4 + u;
#pragma unroll
            for (int b = 0; b < BATCH; ++b) {
                const float yv = s_yin[b * KB + kL];
                acc[b].x = fmaf(yv, m.x, acc[b].x);
                acc[b].y = fmaf(yv, m.y, acc[b].y);
                acc[b].z = fmaf(yv, m.z, acc[b].z);
                acc[b].w = fmaf(yv, m.w, acc[b].w);
            }
        }
    }

    // Store per-wave accumulators: layout s_red[wave][b][COLB]
#pragma unroll
    for (int b = 0; b < BATCH; ++b) {
        *reinterpret_cast<float4*>(&s_red[(wave * BATCH + b) * COLB + lane * 4]) = acc[b];
    }
    __syncthreads();

    // Reduce 4 waves -> partial.  col = t (coalesced LDS + global).
#pragma unroll
    for (int b = 0; b < BATCH; ++b) {
        const int col = t;
        const float s = s_red[(0 * BATCH + b) * COLB + col]
                      + s_red[(1 * BATCH + b) * COLB + col]
                      + s_red[(2 * BATCH + b) * COLB + col]
                      + s_red[(3 * BATCH + b) * COLB + col];
        partial[((size_t)kBlock * BATCH + b) * E + colBlock * COLB + col] = s;
    }
}

// ---------------------------------------------------------------------------
// Kernel B: yout[b][j] = tanh(input[b][j] + sum_kb partial[kb][b][j])
// ---------------------------------------------------------------------------
template <int NKB>
__global__ __launch_bounds__(256) void finalize_yout_kernel(
    const float* __restrict__ input,
    const float* __restrict__ partial,
    float* __restrict__ yout)
{
    const int idx = blockIdx.x * 256 + threadIdx.x;   // 0..32767
    const int b = idx >> 12;
    const int j = idx & (E - 1);

    float s = input[idx];
#pragma unroll 8
    for (int kb = 0; kb < NKB; ++kb)
        s += partial[((size_t)kb * BATCH + b) * E + j];

    yout[idx] = tanhf(s);
}

// ---------------------------------------------------------------------------
// Kernel C: hebb_new = (1-eta)*hebb + eta * outer(yin[0], yout[0])
// hebb read: normal (L3-resident thanks to nt w/alpha). hebb_out store:
// NORMAL (park dirty lines in L3; write-back elided across replays).
// ---------------------------------------------------------------------------
__global__ __launch_bounds__(256) void hebb_update_kernel(
    const float* __restrict__ hebb,
    const float* __restrict__ yin,
    const float* __restrict__ yout,       // d_out row 0 (already written)
    const float* __restrict__ eta_p,
    float* __restrict__ hebb_out)
{
    const float eta  = eta_p[0];
    const float keep = 1.0f - eta;

    const size_t N4 = (size_t)E * E / 4;  // 4,194,304 float4's
    const size_t stride = (size_t)gridDim.x * blockDim.x;

    for (size_t i4 = (size_t)blockIdx.x * blockDim.x + threadIdx.x; i4 < N4; i4 += stride) {
        const size_t base = i4 * 4;
        const int row = (int)(base >> 12);          // i index
        const int jcol = (int)(base & (E - 1));     // j index (multiple of 4)

        const float y0 = yin[row] * eta;            // eta * yin[0][row]
        const float4 h  = *reinterpret_cast<const float4*>(hebb + base);
        const float4 yo = *reinterpret_cast<const float4*>(yout + jcol);

        float4 r;
        r.x = fmaf(y0, yo.x, keep * h.x);
        r.y = fmaf(y0, yo.y, keep * h.y);
        r.z = fmaf(y0, yo.z, keep * h.z);
        r.w = fmaf(y0, yo.w, keep * h.w);

        *reinterpret_cast<float4*>(hebb_out + base) = r;
    }
}

// ---------------------------------------------------------------------------
extern "C" void kernel_launch(void* const* d_in, const int* in_sizes, int n_in,
                              void* d_out, int out_size, void* d_ws, size_t ws_size,
                              hipStream_t stream) {
    const float* input = (const float*)d_in[0];   // [8, 4096]
    const float* yin   = (const float*)d_in[1];   // [8, 4096]
    const float* hebb  = (const float*)d_in[2];   // [4096, 4096]
    const float* w     = (const float*)d_in[3];   // [4096, 4096]
    const float* alpha = (const float*)d_in[4];   // [4096, 4096]
    const float* eta   = (const float*)d_in[5];   // [1]

    float* out      = (float*)d_out;
    float* yout     = out;                               // 8*4096 floats
    float* hebb_out = out + (size_t)BATCH * E;           // 4096*4096 floats
    float* partial  = (float*)d_ws;                      // 4 MiB (KB=128)

    // KB=128: 512 blocks (best measured config), partial = 4 MiB.
    dim3 gridA(E / COLB, E / 128);   // 16 x 32
    partial_gemm_kernel<128><<<gridA, 256, 0, stream>>>(yin, hebb, w, alpha, partial);

    finalize_yout_kernel<32><<<(BATCH * E) / 256, 256, 0, stream>>>(input, partial, yout);

    hebb_update_kernel<<<2048, 256, 0, stream>>>(hebb, yin, yout, eta, hebb_out);
}

// Round 7
// 58.781 us; speedup vs baseline: 1.3042x; 1.3009x over previous
//
#include <hip/hip_runtime.h>
#include <math.h>

// Problem constants
#define E      4096
#define BATCH  8
#define COLB   256            // columns per block (64 lanes x float4)
#define KB     128            // k-rows per block (4 waves x 32)
#define NCOLB  (E / COLB)     // 16
#define NKB    (E / KB)       // 32

typedef float f32x4 __attribute__((ext_vector_type(4)));

// ---------------------------------------------------------------------------
// Kernel A: split-K partial GEMM for  yin @ (w + alpha*hebb)
//   partial[kBlock][b][col] = sum_{k in kBlock} yin[b][k] * (w[k][col] + alpha[k][col]*hebb[k][col])
// Deterministic: fixed partitioning, fixed reduction order, no atomics.
// ALL loads normal (R4/R5 lesson: nt loads force L3 misses, +17 us).
// The L3-residency lever lives in kernel C's nt STORE instead.
// ---------------------------------------------------------------------------
__global__ __launch_bounds__(256) void partial_gemm_kernel(
    const float* __restrict__ yin,
    const float* __restrict__ hebb,
    const float* __restrict__ w,
    const float* __restrict__ alpha,
    float* __restrict__ partial)          // [NKB][BATCH][E]
{
    __shared__ __align__(16) float s_yin[BATCH * KB];        // 4 KiB
    __shared__ __align__(16) float s_red[4 * BATCH * COLB];  // 32 KiB

    const int t    = threadIdx.x;
    const int lane = t & 63;
    const int wave = t >> 6;              // 0..3
    const int colBlock = blockIdx.x;      // 0..15
    const int kBlock   = blockIdx.y;      // 0..31

    // Stage yin[b][kBlock*KB .. +KB) into LDS: 8 x 128 floats, float4 per thread
    {
        const int b   = t >> 5;           // 0..7
        const int off = (t & 31) * 4;     // 0..124
        const float4 v = *reinterpret_cast<const float4*>(
            yin + (size_t)b * E + (size_t)kBlock * KB + off);
        *reinterpret_cast<float4*>(&s_yin[b * KB + off]) = v;
    }
    __syncthreads();

    const int col0 = colBlock * COLB + lane * 4;

    float4 acc[BATCH];
#pragma unroll
    for (int b = 0; b < BATCH; ++b) acc[b] = make_float4(0.f, 0.f, 0.f, 0.f);

    const int kLocal0 = wave * (KB / 4);  // 32 k's per wave

#pragma unroll 2
    for (int kk = 0; kk < KB / 4; ++kk) {
        const int kL = kLocal0 + kk;
        const size_t row = (size_t)(kBlock * KB + kL) * E + col0;

        const float4 w4 = *reinterpret_cast<const float4*>(w + row);
        const float4 a4 = *reinterpret_cast<const float4*>(alpha + row);
        const float4 h4 = *reinterpret_cast<const float4*>(hebb + row);

        float4 m;
        m.x = w4.x + a4.x * h4.x;
        m.y = w4.y + a4.y * h4.y;
        m.z = w4.z + a4.z * h4.z;
        m.w = w4.w + a4.w * h4.w;

#pragma unroll
        for (int b = 0; b < BATCH; ++b) {
            const float yv = s_yin[b * KB + kL];
            acc[b].x = fmaf(yv, m.x, acc[b].x);
            acc[b].y = fmaf(yv, m.y, acc[b].y);
            acc[b].z = fmaf(yv, m.z, acc[b].z);
            acc[b].w = fmaf(yv, m.w, acc[b].w);
        }
    }

    // Store per-wave accumulators: layout s_red[wave][b][COLB]
#pragma unroll
    for (int b = 0; b < BATCH; ++b) {
        *reinterpret_cast<float4*>(&s_red[(wave * BATCH + b) * COLB + lane * 4]) = acc[b];
    }
    __syncthreads();

    // Reduce 4 waves -> partial.  col = t (coalesced LDS + global).
#pragma unroll
    for (int b = 0; b < BATCH; ++b) {
        const int col = t;
        const float s = s_red[(0 * BATCH + b) * COLB + col]
                      + s_red[(1 * BATCH + b) * COLB + col]
                      + s_red[(2 * BATCH + b) * COLB + col]
                      + s_red[(3 * BATCH + b) * COLB + col];
        partial[((size_t)kBlock * BATCH + b) * E + colBlock * COLB + col] = s;
    }
}

// ---------------------------------------------------------------------------
// Kernel B: yout[b][j] = tanh(input[b][j] + sum_kb partial[kb][b][j])
// ---------------------------------------------------------------------------
__global__ __launch_bounds__(256) void finalize_yout_kernel(
    const float* __restrict__ input,
    const float* __restrict__ partial,
    float* __restrict__ yout)
{
    const int idx = blockIdx.x * 256 + threadIdx.x;   // 0..32767
    const int b = idx >> 12;
    const int j = idx & (E - 1);

    float s = input[idx];
#pragma unroll
    for (int kb = 0; kb < NKB; ++kb)
        s += partial[((size_t)kb * BATCH + b) * E + j];

    yout[idx] = tanhf(s);
}

// ---------------------------------------------------------------------------
// Kernel C: hebb_new = (1-eta)*hebb + eta * outer(yin[0], yout[0])
// hebb read: NORMAL (L3-resident across replays). hebb_out store:
// NON-TEMPORAL — hebb_out is never re-read on device; streaming it past L3
// shrinks the resident set to w+alpha+hebb+partial ~= 196 MiB < 256 MiB L3,
// so the GEMM inputs stay cached across graph replays.
// ---------------------------------------------------------------------------
__global__ __launch_bounds__(256) void hebb_update_kernel(
    const float* __restrict__ hebb,
    const float* __restrict__ yin,
    const float* __restrict__ yout,       // d_out row 0 (already written)
    const float* __restrict__ eta_p,
    float* __restrict__ hebb_out)
{
    const float eta  = eta_p[0];
    const float keep = 1.0f - eta;

    const size_t N4 = (size_t)E * E / 4;  // 4,194,304 float4's
    const size_t stride = (size_t)gridDim.x * blockDim.x;

    for (size_t i4 = (size_t)blockIdx.x * blockDim.x + threadIdx.x; i4 < N4; i4 += stride) {
        const size_t base = i4 * 4;
        const int row = (int)(base >> 12);          // i index
        const int jcol = (int)(base & (E - 1));     // j index (multiple of 4)

        const float y0 = yin[row] * eta;            // eta * yin[0][row]
        const float4 h  = *reinterpret_cast<const float4*>(hebb + base);
        const float4 yo = *reinterpret_cast<const float4*>(yout + jcol);

        f32x4 r;
        r.x = fmaf(y0, yo.x, keep * h.x);
        r.y = fmaf(y0, yo.y, keep * h.y);
        r.z = fmaf(y0, yo.z, keep * h.z);
        r.w = fmaf(y0, yo.w, keep * h.w);

        __builtin_nontemporal_store(r, reinterpret_cast<f32x4*>(hebb_out + base));
    }
}

// ---------------------------------------------------------------------------
extern "C" void kernel_launch(void* const* d_in, const int* in_sizes, int n_in,
                              void* d_out, int out_size, void* d_ws, size_t ws_size,
                              hipStream_t stream) {
    const float* input = (const float*)d_in[0];   // [8, 4096]
    const float* yin   = (const float*)d_in[1];   // [8, 4096]
    const float* hebb  = (const float*)d_in[2];   // [4096, 4096]
    const float* w     = (const float*)d_in[3];   // [4096, 4096]
    const float* alpha = (const float*)d_in[4];   // [4096, 4096]
    const float* eta   = (const float*)d_in[5];   // [1]

    float* out      = (float*)d_out;
    float* yout     = out;                               // 8*4096 floats
    float* hebb_out = out + (size_t)BATCH * E;           // 4096*4096 floats
    float* partial  = (float*)d_ws;                      // 4 MiB

    dim3 gridA(NCOLB, NKB);   // 16 x 32 = 512 blocks
    partial_gemm_kernel<<<gridA, 256, 0, stream>>>(yin, hebb, w, alpha, partial);

    finalize_yout_kernel<<<(BATCH * E) / 256, 256, 0, stream>>>(input, partial, yout);

    hebb_update_kernel<<<2048, 256, 0, stream>>>(hebb, yin, yout, eta, hebb_out);
}